// Round 5
// baseline (99.322 us; speedup 1.0000x reference)
//
#include <hip/hip_runtime.h>

#define CIN 27
#define C0  14           // first channel chunk
#define C1  13           // second channel chunk
#define HH 64
#define WW 64
#define OC 32
#define TW 16            // tile width (pixels)
#define TH 16            // tile height (pixels)
#define RS 24            // LDS row stride (dwords). Row starts mod 32: {0,24,16,8} -> 16-dword
                         // runs tile all 32 banks exactly 2x per 4 rows => conflict-free (m136)
#define CS (18 * RS)     // 432 dwords per channel slab
#define WS 12            // padded per-channel weight stride (48B, 16B-aligned)

__device__ __forceinline__ float maj3(float a, float b, float c) {
    // Exact closed form of bipolar 3-input majority gate: (a + b + c - a*b*c)/2
    float s = a + b + c;
    return 0.5f * fmaf(-(a * b), c, s);
}

__device__ __forceinline__ float2 pk_maj3(float2 a, float2 b, float2 c) {
    float2 r;
    r.x = maj3(a.x, b.x, c.x);
    r.y = maj3(a.y, b.y, c.y);
    return r;
}

struct SmemT {
    float sw[CIN * WS];                  // 1296 B
    __align__(16) float sx[C0 * CS];     // 14*432*4 = 24192 B   (total ~25.5 KB -> 6 blocks/CU)
};

template <int CBASE, int CNUM>
__device__ __forceinline__ void stage_chunk(SmemT& sm, const float* __restrict__ xn,
                                            int tid, int tile_h0, int tile_w0) {
    #pragma unroll
    for (int i = 0; i < 4; ++i) {
        int slot = tid + 128 * i;            // 0..511, covers CS=432
        if (slot < CS) {
            int r   = slot / RS;             // 0..17
            int col = slot - r * RS;         // 0..23 (18..23 are pad)
            int gr = tile_h0 + r - 1;
            int gc = tile_w0 + col - 1;
            bool ok = (col < 18) & ((unsigned)gr < (unsigned)HH) & ((unsigned)gc < (unsigned)WW);
            int off = ok ? (gr * WW + gc) : 0;   // clamp addr; select after load (branchless, safe)
            #pragma unroll
            for (int c = 0; c < CNUM; ++c) {
                float raw = xn[(size_t)(CBASE + c) * (HH * WW) + off];
                sm.sx[c * CS + slot] = ok ? raw : 0.0f;   // consecutive lanes -> consecutive dwords
            }
        }
    }
}

template <int CBASE, int CNUM>
__device__ __forceinline__ void compute_chunk(const SmemT& sm, float2* m2,
                                              int tx, int ty) {
    #pragma unroll
    for (int c = 0; c < CNUM; ++c) {
        const int cg = CBASE + c;
        float4 wa = *(const float4*)&sm.sw[cg * WS];      // broadcast reads: conflict-free
        float4 wb = *(const float4*)&sm.sw[cg * WS + 4];
        float  w8 = sm.sw[cg * WS + 8];
        const float wk[9] = {wa.x, wa.y, wa.z, wa.w, wb.x, wb.y, wb.z, wb.w, w8};

        float2 m1[3];
        #pragma unroll
        for (int ki = 0; ki < 3; ++ki) {
            // base dword even (CS,RS,2tx all even) -> two aligned ds_read_b64
            const float2* prow = (const float2*)&sm.sx[c * CS + (ty + ki) * RS + 2 * tx];
            float2 v01 = prow[0];   // cols 2tx, 2tx+1
            float2 v23 = prow[1];   // cols 2tx+2, 2tx+3
            float w0 = wk[ki * 3 + 0], w1 = wk[ki * 3 + 1], w2 = wk[ki * 3 + 2];
            // pixel A (col 2tx): v01.x,v01.y,v23.x ; pixel B (col 2tx+1): v01.y,v23.x,v23.y
            float2 p0 = make_float2(v01.x * w0, v01.y * w0);
            float2 p1 = make_float2(v01.y * w1, v23.x * w1);
            float2 p2 = make_float2(v23.x * w2, v23.y * w2);
            m1[ki] = pk_maj3(p0, p1, p2);
        }
        m2[cg] = pk_maj3(m1[0], m1[1], m1[2]);
    }
}

__global__ __launch_bounds__(128) void sconv_maj_kernel(
    const float* __restrict__ x,    // [N, CIN, 64, 64]
    const float* __restrict__ wgt,  // [OC, CIN, 3, 3]
    float* __restrict__ out)        // [N, OC, 64, 64]
{
    __shared__ SmemT sm;

    const int tx = threadIdx.x;            // 0..7  (pixel cols 2tx, 2tx+1)
    const int ty = threadIdx.y;            // 0..15
    const int tid = ty * 8 + tx;
    const int tile_w0 = blockIdx.x * TW;
    const int tile_h0 = blockIdx.y * TH;
    const int n  = blockIdx.z >> 5;        // OC = 32
    const int oc = blockIdx.z & 31;

    // ---- stage all weights once (block-uniform oc) ----
    for (int i = tid; i < CIN * 9; i += 128) {
        int c = i / 9;
        int k = i - 9 * c;
        sm.sw[c * WS + k] = wgt[oc * (CIN * 9) + i];
    }

    const float* xn = x + (size_t)n * (CIN * HH * WW);
    float2 m2[CIN];

    // ---- chunk 0: channels [0,14) ----
    stage_chunk<0, C0>(sm, xn, tid, tile_h0, tile_w0);
    __syncthreads();
    compute_chunk<0, C0>(sm, m2, tx, ty);
    __syncthreads();                        // all readers done before restage

    // ---- chunk 1: channels [14,27) ----
    stage_chunk<C0, C1>(sm, xn, tid, tile_h0, tile_w0);
    __syncthreads();
    compute_chunk<C0, C1>(sm, m2, tx, ty);

    // ---- remaining tree levels (c-major order preserved) ----
    float2 m3[9];
    #pragma unroll
    for (int g = 0; g < 9; ++g)
        m3[g] = pk_maj3(m2[3 * g], m2[3 * g + 1], m2[3 * g + 2]);
    float2 m4a = pk_maj3(m3[0], m3[1], m3[2]);
    float2 m4b = pk_maj3(m3[3], m3[4], m3[5]);
    float2 m4c = pk_maj3(m3[6], m3[7], m3[8]);
    float2 res = pk_maj3(m4a, m4b, m4c);

    const int h = tile_h0 + ty;
    const int w = tile_w0 + 2 * tx;
    float2* po = (float2*)(out + (((size_t)n * OC + oc) * HH + h) * WW + w);
    *po = res;
}

extern "C" void kernel_launch(void* const* d_in, const int* in_sizes, int n_in,
                              void* d_out, int out_size, void* d_ws, size_t ws_size,
                              hipStream_t stream) {
    const float* x   = (const float*)d_in[0];
    const float* wgt = (const float*)d_in[1];
    float* out = (float*)d_out;

    dim3 block(8, 16, 1);                 // 128 threads, 2 waves
    dim3 grid(WW / TW, HH / TH, 2 * OC);  // (4,4,64) = 1024 blocks; 25.5KB LDS -> 6 blocks/CU cap,
                                          // 4/CU needed -> entire grid co-resident, 12 waves/CU
    sconv_maj_kernel<<<grid, block, 0, stream>>>(x, wgt, out);
}

// Round 6
// 69.943 us; speedup vs baseline: 1.4201x; 1.4201x over previous
//
#include <hip/hip_runtime.h>

#define CIN 27
#define HH 64
#define WW 64
#define OC 32
#define TW 16            // tile width (pixels)
#define TH 16            // tile height (pixels)
#define RS 20            // LDS row stride (dwords). EVEN -> every compute row read is two
                         // aligned ds_read_b64 (RS=19 broke merge on half the rows)
#define CS (18 * RS)     // 360 dwords per channel slab
#define WS 12            // padded per-channel weight stride (48B, 16B-aligned)
// LDS: 27*360*4 + 27*12*4 = 38880 + 1296 = 40176 B <= 40960 -> exactly 4 blocks/CU

__device__ __forceinline__ float maj3(float a, float b, float c) {
    // Exact closed form of bipolar 3-input majority gate: (a + b + c - a*b*c)/2
    float s = a + b + c;
    return 0.5f * fmaf(-(a * b), c, s);
}

__device__ __forceinline__ float2 pk_maj3(float2 a, float2 b, float2 c) {
    float2 r;
    r.x = maj3(a.x, b.x, c.x);
    r.y = maj3(a.y, b.y, c.y);
    return r;
}

__global__ __launch_bounds__(128) void sconv_maj_kernel(
    const float* __restrict__ x,    // [N, CIN, 64, 64]
    const float* __restrict__ wgt,  // [OC, CIN, 3, 3]
    float* __restrict__ out)        // [N, OC, 64, 64]
{
    __shared__ __align__(16) float sw[CIN * WS];
    __shared__ __align__(16) float sx[CIN * CS];

    const int tx = threadIdx.x;            // 0..7  (pixel cols 2tx, 2tx+1)
    const int ty = threadIdx.y;            // 0..15
    const int tid = ty * 8 + tx;
    const int tile_w0 = blockIdx.x * TW;
    const int tile_h0 = blockIdx.y * TH;
    const int n  = blockIdx.z >> 5;        // OC = 32
    const int oc = blockIdx.z & 31;

    // ---- stage weights (block-uniform oc) into padded LDS slots ----
    for (int i = tid; i < CIN * 9; i += 128) {
        int c = i / 9;
        int k = i - 9 * c;
        sw[c * WS + k] = wgt[oc * (CIN * 9) + i];
    }

    // ---- stage x tile with 1-halo (single pass, all 27 channels) ----
    const float* xn = x + (size_t)n * (CIN * HH * WW);
    for (int pos = tid; pos < 18 * 18; pos += 128) {
        int r   = pos / 18;
        int col = pos - 18 * r;
        int gr = tile_h0 + r - 1;
        int gc = tile_w0 + col - 1;
        bool ok = ((unsigned)gr < (unsigned)HH) & ((unsigned)gc < (unsigned)WW);
        int off = ok ? (gr * WW + gc) : 0;     // clamped addr, select after load
        float* lp = sx + r * RS + col;
        #pragma unroll
        for (int c = 0; c < CIN; ++c) {
            float raw = xn[(size_t)c * (HH * WW) + off];
            lp[c * CS] = ok ? raw : 0.0f;
        }
    }
    __syncthreads();

    // ---- 5-level majority tree, folded as-you-go (minimal live registers) ----
    // feature order f = c*9 + ki*3 + kj is preserved: u is innermost channel.
    float2 m4[3];
    #pragma unroll
    for (int q = 0; q < 3; ++q) {              // level-4 group (9 channels each)
        float2 m3[3];
        #pragma unroll
        for (int t = 0; t < 3; ++t) {          // level-3 group (3 channels each)
            float2 m2[3];
            #pragma unroll
            for (int u = 0; u < 3; ++u) {      // channel within triple
                const int c = q * 9 + t * 3 + u;
                float4 wa = *(const float4*)&sw[c * WS];      // w0..w3 (broadcast)
                float4 wb = *(const float4*)&sw[c * WS + 4];  // w4..w7
                float  w8 = sw[c * WS + 8];
                const float wk[9] = {wa.x, wa.y, wa.z, wa.w,
                                     wb.x, wb.y, wb.z, wb.w, w8};
                float2 m1[3];
                #pragma unroll
                for (int ki = 0; ki < 3; ++ki) {
                    // base dword = c*360 + (ty+ki)*20 + 2tx : even -> two aligned b64
                    const float2* prow =
                        (const float2*)&sx[c * CS + (ty + ki) * RS + 2 * tx];
                    float2 v01 = prow[0];   // cols 2tx, 2tx+1
                    float2 v23 = prow[1];   // cols 2tx+2, 2tx+3
                    float w0 = wk[ki * 3 + 0];
                    float w1 = wk[ki * 3 + 1];
                    float w2 = wk[ki * 3 + 2];
                    // pixel A (col 2tx): v01.x v01.y v23.x ; pixel B: v01.y v23.x v23.y
                    float2 p0 = make_float2(v01.x * w0, v01.y * w0);
                    float2 p1 = make_float2(v01.y * w1, v23.x * w1);
                    float2 p2 = make_float2(v23.x * w2, v23.y * w2);
                    m1[ki] = pk_maj3(p0, p1, p2);
                }
                m2[u] = pk_maj3(m1[0], m1[1], m1[2]);
            }
            m3[t] = pk_maj3(m2[0], m2[1], m2[2]);   // fold immediately
        }
        m4[q] = pk_maj3(m3[0], m3[1], m3[2]);       // fold immediately
    }
    float2 res = pk_maj3(m4[0], m4[1], m4[2]);

    const int h = tile_h0 + ty;
    const int w = tile_w0 + 2 * tx;
    float2* po = (float2*)(out + (((size_t)n * OC + oc) * HH + h) * WW + w);
    *po = res;
}

extern "C" void kernel_launch(void* const* d_in, const int* in_sizes, int n_in,
                              void* d_out, int out_size, void* d_ws, size_t ws_size,
                              hipStream_t stream) {
    const float* x   = (const float*)d_in[0];
    const float* wgt = (const float*)d_in[1];
    float* out = (float*)d_out;

    dim3 block(8, 16, 1);                 // 128 threads, 2 waves
    dim3 grid(WW / TW, HH / TH, 2 * OC);  // (4,4,64) = 1024 blocks, 4/CU, fully resident
    sconv_maj_kernel<<<grid, block, 0, stream>>>(x, wgt, out);
}